// Round 3
// baseline (1111.111 us; speedup 1.0000x reference)
//
#include <hip/hip_runtime.h>
#include <hip/hip_bf16.h>

// ModernNCA fused pipeline for MI355X (gfx950). Round 3: fix register spills.
//
//  R2 lesson: persistent a[16]+acc[16] needed >128 VGPRs -> compiler spilled in
//  the hot loop (VGPR_Count=120 < required), FETCH 414MB, all pipes idle.
//  R3 dist: 32x32x16 MFMA (2x FLOP per fragment byte), block 128x128, wave
//  64x64 = 2x2 tiles -> acc exactly 64 VGPRs, nothing else persistent.
//  Single-buffer LDS (39 KB) -> 4 blocks/CU (50% occupancy), 2-barrier K-loop,
//  global_load_lds staging for both q-slice and c-slice.
//
//  Padding: 5000->5120 per chunk; pad rows c=0, csq=1e4 -> d>=94 -> ed==0 (or
//  denormal ~1e-41); each pad adds exp(0)=1 to sumexp, finalize subtracts 120.

typedef _Float16 f16x8 __attribute__((ext_vector_type(8)));
typedef _Float16 f16x4 __attribute__((ext_vector_type(4)));
typedef float f32x4 __attribute__((ext_vector_type(4)));
typedef float f32x16 __attribute__((ext_vector_type(16)));

#define MFMA16(a, b, c) __builtin_amdgcn_mfma_f32_16x16x32_f16(a, b, c, 0, 0, 0)
#define MFMA32(a, b, c) __builtin_amdgcn_mfma_f32_32x32x16_f16(a, b, c, 0, 0, 0)

#define GLL16(gp, lp)                                                          \
  __builtin_amdgcn_global_load_lds(                                            \
      (const __attribute__((address_space(1))) unsigned int*)(gp),             \
      (__attribute__((address_space(3))) unsigned int*)(lp), 16, 0, 0)

// ---------------- prep: W1t/W2t transpose+cast, padded y, zero accumulators
__global__ __launch_bounds__(256) void prep_kernel(
    const float* __restrict__ W1, const float* __restrict__ W2,
    const int* __restrict__ y, _Float16* __restrict__ w1t,
    _Float16* __restrict__ w2t, int* __restrict__ ypad,
    float* __restrict__ zero_base) {
  int idx = blockIdx.x * 256 + threadIdx.x;
  if (idx < 49152) {                       // W1 [96,512] -> W1t [512,96]
    int n = idx / 96, k = idx - n * 96;
    w1t[idx] = (_Float16)W1[k * 512 + n];
  } else if (idx < 311296) {               // W2 [512,512] -> W2t [512,512]
    int j = idx - 49152;
    int n = j / 512, k = j - n * 512;
    w2t[j] = (_Float16)W2[k * 512 + n];
  } else if (idx < 413696) {               // padded candidate_y
    int j = idx - 311296;
    int ch = j / 5120, pos = j - ch * 5120;
    ypad[j] = (pos < 5000) ? y[ch * 5000 + pos] : 0;
  } else if (idx < 547840) {
    zero_base[idx - 413696] = 0.0f;        // csq | qsq | sumexp | logits
  }
}

// ---------------- fused 2-layer encoder: enc = relu(x@W1+b1)@W2 + b2
// 32 rows/block. A = weight cols (global, L2-hot), B = data rows (swizzled
// LDS). No manual register pipelining (that spilled in R2).
template <int CHUNK_IN, int CHUNK_OUT>
__global__ __launch_bounds__(256, 4) void encode_kernel(
    const float* __restrict__ xn, const float* __restrict__ xc,
    const _Float16* __restrict__ w1t, const float* __restrict__ b1,
    const _Float16* __restrict__ w2t, const float* __restrict__ b2,
    _Float16* __restrict__ out, float* __restrict__ outsq) {
  __shared__ __align__(16) char lds_x[8192];   // 32 rows x 16 units(16B) swizzled
  __shared__ __align__(16) char lds_h[32768];  // 32 rows x 64 units(16B) swizzled

  const int t = threadIdx.x;
  const int R0 = blockIdx.x * 32;
  const int w = t >> 6, l = t & 63;
  const int l15 = l & 15, quad = l >> 4;
  const int ncol0 = w * 128;

  // ---- stage x (f32 -> f16, swizzled): unit kq of row holds cols kq*8..+8
#pragma unroll
  for (int it = 0; it < 2; it++) {
    int idx = it * 256 + t;
    int row = idx >> 4, kq = idx & 15;
    int pr = R0 + row;
    int ch = pr / CHUNK_OUT, pos = pr - ch * CHUNK_OUT;
    float v[8] = {0, 0, 0, 0, 0, 0, 0, 0};
    if (pos < CHUNK_IN && kq < 12) {
      int orig = ch * CHUNK_IN + pos;
      float4 f0, f1;
      if (kq < 8) {
        f0 = *(const float4*)&xn[orig * 64 + kq * 8];
        f1 = *(const float4*)&xn[orig * 64 + kq * 8 + 4];
      } else {
        f0 = *(const float4*)&xc[orig * 32 + (kq - 8) * 8];
        f1 = *(const float4*)&xc[orig * 32 + (kq - 8) * 8 + 4];
      }
      v[0] = f0.x; v[1] = f0.y; v[2] = f0.z; v[3] = f0.w;
      v[4] = f1.x; v[5] = f1.y; v[6] = f1.z; v[7] = f1.w;
    }
    f16x8 hv;
#pragma unroll
    for (int j = 0; j < 8; j++) hv[j] = (_Float16)v[j];
    *(f16x8*)&lds_x[row * 256 + (((kq ^ (row & 7)) & 15) << 4)] = hv;
  }
  __syncthreads();

  // ---- phase 1: h = x @ W1  (K=96)
  f32x4 acc1[8][2];
#pragma unroll
  for (int ni = 0; ni < 8; ni++)
#pragma unroll
    for (int rt = 0; rt < 2; rt++) acc1[ni][rt] = (f32x4)(0.0f);

#pragma unroll
  for (int kt = 0; kt < 3; kt++) {
    f16x8 bx[2];
#pragma unroll
    for (int rt = 0; rt < 2; rt++) {
      int row = rt * 16 + l15;
      int kq = kt * 4 + quad;
      bx[rt] = *(const f16x8*)&lds_x[row * 256 + ((kq ^ (row & 7)) << 4)];
    }
#pragma unroll
    for (int ni = 0; ni < 8; ni++) {
      f16x8 aw = *(const f16x8*)&w1t[(ncol0 + ni * 16 + l15) * 96 + kt * 32 + quad * 8];
#pragma unroll
      for (int rt = 0; rt < 2; rt++) acc1[ni][rt] = MFMA16(aw, bx[rt], acc1[ni][rt]);
    }
  }

  // ---- epilogue 1: +b1, relu, b64 write to swizzled lds_h
#pragma unroll
  for (int ni = 0; ni < 8; ni++) {
    float4 b1v = *(const float4*)&b1[ncol0 + ni * 16 + quad * 4];
    int kq2 = (ncol0 >> 3) + ni * 2 + (quad >> 1);
#pragma unroll
    for (int rt = 0; rt < 2; rt++) {
      int row = rt * 16 + l15;
      f16x4 hv;
      hv[0] = (_Float16)fmaxf(acc1[ni][rt][0] + b1v.x, 0.0f);
      hv[1] = (_Float16)fmaxf(acc1[ni][rt][1] + b1v.y, 0.0f);
      hv[2] = (_Float16)fmaxf(acc1[ni][rt][2] + b1v.z, 0.0f);
      hv[3] = (_Float16)fmaxf(acc1[ni][rt][3] + b1v.w, 0.0f);
      int swz = (kq2 & ~7) | ((kq2 & 7) ^ (row & 7));
      *(f16x4*)&lds_h[row * 1024 + (swz << 4) + ((quad & 1) << 3)] = hv;
    }
  }
  __syncthreads();

  // ---- phase 2: enc = h @ W2  (K=512), direct loads (no manual pipelining)
  f32x4 acc2[8][2];
#pragma unroll
  for (int ni = 0; ni < 8; ni++)
#pragma unroll
    for (int rt = 0; rt < 2; rt++) acc2[ni][rt] = (f32x4)(0.0f);

#pragma unroll 2
  for (int kt = 0; kt < 16; kt++) {
    f16x8 bh[2];
#pragma unroll
    for (int rt = 0; rt < 2; rt++) {
      int row = rt * 16 + l15;
      int kq = kt * 4 + quad;
      int swz = (kq & ~7) | ((kq & 7) ^ (row & 7));
      bh[rt] = *(const f16x8*)&lds_h[row * 1024 + (swz << 4)];
    }
#pragma unroll
    for (int ni = 0; ni < 8; ni++) {
      f16x8 aw = *(const f16x8*)&w2t[(ncol0 + ni * 16 + l15) * 512 + kt * 32 + quad * 8];
#pragma unroll
      for (int rt = 0; rt < 2; rt++)
        acc2[ni][rt] = MFMA16(aw, bh[rt], acc2[ni][rt]);
    }
  }

  // ---- epilogue 2: +b2, b64 global store, row sum-of-squares
#pragma unroll
  for (int rt = 0; rt < 2; rt++) {
    int pr = R0 + rt * 16 + l15;
    int ch = pr / CHUNK_OUT, pos = pr - ch * CHUNK_OUT;
    bool valid = pos < CHUNK_IN;
    float s = 0.0f;
#pragma unroll
    for (int ni = 0; ni < 8; ni++) {
      float4 b2v = *(const float4*)&b2[ncol0 + ni * 16 + quad * 4];
      f16x4 ov;
      if (valid) {
        ov[0] = (_Float16)(acc2[ni][rt][0] + b2v.x);
        ov[1] = (_Float16)(acc2[ni][rt][1] + b2v.y);
        ov[2] = (_Float16)(acc2[ni][rt][2] + b2v.z);
        ov[3] = (_Float16)(acc2[ni][rt][3] + b2v.w);
#pragma unroll
        for (int r = 0; r < 4; r++) {
          float cv = (float)ov[r];
          s += cv * cv;
        }
      } else {
        ov[0] = (_Float16)0.0f; ov[1] = (_Float16)0.0f;
        ov[2] = (_Float16)0.0f; ov[3] = (_Float16)0.0f;
        s += 4.0f * 19.53125f;               // 1e4 / 512 per pad element
      }
      *(f16x4*)&out[pr * 512 + ncol0 + ni * 16 + quad * 4] = ov;
    }
    s += __shfl_xor(s, 16);
    s += __shfl_xor(s, 32);
    if (quad == 0) atomicAdd(&outsq[pr], s);  // 4 adds/row (one per wave)
  }
}

// ---------------- fused distance + reductions (32x32x16 MFMA)
// grid (8 by fast, 800 bx slow). Block: 128 q-rows x 128 c-cols, 4 waves of
// 64x64 (2x2 tiles of 32x32). acc = 64 VGPRs persistent; a/b transient from
// single-buffered swizzled LDS staged by global_load_lds. K-loop: 8 x K=64.
__global__ __launch_bounds__(256, 4) void dist_kernel(
    const _Float16* __restrict__ q, const _Float16* __restrict__ c,
    const float* __restrict__ qsq, const float* __restrict__ csq,
    const int* __restrict__ ypad, float* __restrict__ sumexp,
    float* __restrict__ logits) {
  __shared__ __align__(16) char lds_q[16384];  // 128 rows x 8 units(16B) swz
  __shared__ __align__(16) char lds_c[16384];  // 128 cols x 8 units(16B) swz
  __shared__ float lds_logit[1280];            // 128 rows x 10 classes
  __shared__ float lds_qsq[128];
  __shared__ float lds_csq[128];
  __shared__ int   lds_y[128];

  const int t = threadIdx.x, w = t >> 6, l = t & 63;
  const int l31 = l & 31, half = l >> 5;
  const int by = blockIdx.x, bx = blockIdx.y;
  const int wrow = (w & 1) * 64, wcol = (w >> 1) * 64;

  for (int i = t; i < 1280; i += 256) lds_logit[i] = 0.0f;
  if (t < 128) {
    lds_qsq[t] = qsq[by * 128 + t];
    lds_csq[t] = csq[bx * 128 + t];
    lds_y[t]   = ypad[bx * 128 + t];
  }

  const _Float16* cg = c + (size_t)bx * 128 * 512;
  const _Float16* qg = q + (size_t)by * 128 * 512;

  const int lg = w * 8 + (l >> 3);   // row/col subgroup within 32-block
  const int lpos = l & 7;            // 16B position within 128B row

  // stage kb = 0 (both q-slice and c-slice)
#pragma unroll
  for (int i = 0; i < 4; i++) {
    int rc = i * 32 + lg;
    int u = lpos ^ (rc & 7);
    GLL16(cg + rc * 512 + u * 8, lds_c + i * 4096 + w * 1024);
    GLL16(qg + rc * 512 + u * 8, lds_q + i * 4096 + w * 1024);
  }

  f32x16 acc[2][2];
#pragma unroll
  for (int rt = 0; rt < 2; rt++)
#pragma unroll
    for (int ct = 0; ct < 2; ct++) acc[rt][ct] = (f32x16)(0.0f);

  for (int kb = 0; kb < 8; kb++) {
    __syncthreads();   // vmcnt(0) drain: this kb's slices are in LDS
#pragma unroll
    for (int ks = 0; ks < 4; ks++) {
      f16x8 a[2], b[2];
#pragma unroll
      for (int rt = 0; rt < 2; rt++) {
        int row = wrow + rt * 32 + l31;
        int p = (ks * 2 + half) ^ (row & 7);
        a[rt] = *(const f16x8*)&lds_q[row * 128 + p * 16];
      }
#pragma unroll
      for (int ct = 0; ct < 2; ct++) {
        int col = wcol + ct * 32 + l31;
        int p = (ks * 2 + half) ^ (col & 7);
        b[ct] = *(const f16x8*)&lds_c[col * 128 + p * 16];
      }
#pragma unroll
      for (int rt = 0; rt < 2; rt++)
#pragma unroll
        for (int ct = 0; ct < 2; ct++)
          acc[rt][ct] = MFMA32(a[rt], b[ct], acc[rt][ct]);
    }
    if (kb < 7) {
      __syncthreads();  // all waves done reading before overwrite
      const _Float16* cgk = cg + (kb + 1) * 64;
      const _Float16* qgk = qg + (kb + 1) * 64;
#pragma unroll
      for (int i = 0; i < 4; i++) {
        int rc = i * 32 + lg;
        int u = lpos ^ (rc & 7);
        GLL16(cgk + rc * 512 + u * 8, lds_c + i * 4096 + w * 1024);
        GLL16(qgk + rc * 512 + u * 8, lds_q + i * 4096 + w * 1024);
      }
    }
  }

  // epilogue: C/D 32x32 layout row=(reg&3)+8*(reg>>2)+4*half, col=l31
  const int chunk = bx / 40;     // 40 x 128-col tiles per 5120-chunk
#pragma unroll
  for (int rt = 0; rt < 2; rt++) {
#pragma unroll
    for (int reg = 0; reg < 16; reg++) {
      int rloc = wrow + rt * 32 + (reg & 3) + 8 * (reg >> 2) + 4 * half;
      float qs = lds_qsq[rloc];
      float s = 0.0f;
#pragma unroll
      for (int ct = 0; ct < 2; ct++) {
        int cloc = wcol + ct * 32 + l31;
        float sq = qs + lds_csq[cloc] - 2.0f * acc[rt][ct][reg];
        float d = sqrtf(fmaxf(sq, 0.0f));
        float ed = __expf(-d);               // pad cols: d>=94 -> ed ~ 0
        atomicAdd(&lds_logit[rloc * 10 + lds_y[cloc]], ed);
        s += __expf(ed);                     // pad contributes exactly 1.0
      }
      s += __shfl_xor(s, 1);
      s += __shfl_xor(s, 2);
      s += __shfl_xor(s, 4);
      s += __shfl_xor(s, 8);
      s += __shfl_xor(s, 16);
      if (l31 == 0)
        atomicAdd(&sumexp[(by * 128 + rloc) * 20 + chunk], s);
    }
  }
  __syncthreads();
  for (int i = t; i < 1280; i += 256)
    atomicAdd(&logits[by * 1280 + i], lds_logit[i]);
}

// ---------------- finalize: out[i,k] = log(logits[i,k]) - sum_ch log(sumexp-120)
__global__ __launch_bounds__(256) void finalize_kernel(
    const float* __restrict__ logits, const float* __restrict__ sumexp,
    float* __restrict__ out) {
  int i = blockIdx.x * 256 + threadIdx.x;
  if (i >= 1024) return;
  float lse = 0.0f;
#pragma unroll
  for (int ch = 0; ch < 20; ch++) lse += logf(sumexp[i * 20 + ch] - 120.0f);
#pragma unroll
  for (int k = 0; k < 10; k++) out[i * 10 + k] = logf(logits[i * 10 + k]) - lse;
}

extern "C" void kernel_launch(void* const* d_in, const int* in_sizes, int n_in,
                              void* d_out, int out_size, void* d_ws, size_t ws_size,
                              hipStream_t stream) {
  const float* x_num = (const float*)d_in[0];
  const float* x_cat = (const float*)d_in[1];
  const float* cxn   = (const float*)d_in[2];
  const float* cxc   = (const float*)d_in[3];
  const int*   cy    = (const int*)d_in[4];
  const float* W1    = (const float*)d_in[5];
  const float* b1    = (const float*)d_in[6];
  const float* W2    = (const float*)d_in[7];
  const float* b2    = (const float*)d_in[8];
  float* out = (float*)d_out;

  char* ws = (char*)d_ws;
  _Float16* c    = (_Float16*)(ws + 0);           // 102400*512*2 = 104857600
  _Float16* qe   = (_Float16*)(ws + 104857600);   // 1024*512*2   = 1048576
  _Float16* w1t  = (_Float16*)(ws + 105906176);   // 512*96*2     = 98304
  _Float16* w2t  = (_Float16*)(ws + 106004480);   // 512*512*2    = 524288
  float*    csq  = (float*)(ws + 106528768);      // 102400*4     = 409600
  float*    qsq  = (float*)(ws + 106938368);      // 1024*4       = 4096
  float*    sume = (float*)(ws + 106942464);      // 1024*20*4    = 81920
  float*    lgts = (float*)(ws + 107024384);      // 1024*10*4    = 40960
  int*      ypad = (int*)(ws + 107065344);        // 102400*4     = 409600

  prep_kernel<<<2140, 256, 0, stream>>>(W1, W2, cy, w1t, w2t, ypad, csq);
  encode_kernel<5000, 5120><<<3200, 256, 0, stream>>>(cxn, cxc, w1t, b1, w2t, b2, c, csq);
  encode_kernel<(1 << 20), (1 << 20)><<<32, 256, 0, stream>>>(x_num, x_cat, w1t, b1, w2t, b2, qe, qsq);
  dist_kernel<<<dim3(8, 800), 256, 0, stream>>>(qe, c, qsq, csq, ypad, sume, lgts);
  finalize_kernel<<<4, 256, 0, stream>>>(lgts, sume, out);
}

// Round 4
// 1002.588 us; speedup vs baseline: 1.1082x; 1.1082x over previous
//
#include <hip/hip_runtime.h>
#include <hip/hip_bf16.h>

// ModernNCA fused pipeline for MI355X (gfx950). Round 4: barrier-free dist.
//
// R3 lesson: GLL + vmcnt(0)+barrier per kb convoys all waves into synchronized
// full-latency stalls (~105us wall per block for ~5us work); by-blocks sharing
// a c-slice land on different XCDs (no L2 reuse, FETCH=4x c).
// R4 dist: q-slice in LDS once per block; c streamed global->VGPR b-frags
// (no barriers, no GLL in the K loop); XCD-aware column ownership so c is
// HBM-fetched once and re-read from the owning XCD's L2; sumexp in registers.
//
// Padding: 5000->5120 per chunk; pad rows c=0, csq=1e4 -> d>=100 -> ed==0;
// each pad adds exp(0)=1 to chunk sumexp; finalize subtracts 120.

typedef _Float16 f16x8 __attribute__((ext_vector_type(8)));
typedef _Float16 f16x4 __attribute__((ext_vector_type(4)));
typedef float f32x4 __attribute__((ext_vector_type(4)));
typedef float f32x16 __attribute__((ext_vector_type(16)));

#define MFMA16(a, b, c) __builtin_amdgcn_mfma_f32_16x16x32_f16(a, b, c, 0, 0, 0)
#define MFMA32(a, b, c) __builtin_amdgcn_mfma_f32_32x32x16_f16(a, b, c, 0, 0, 0)

// ---------------- prep: W1t/W2t transpose+cast, padded y, zero accumulators
__global__ __launch_bounds__(256) void prep_kernel(
    const float* __restrict__ W1, const float* __restrict__ W2,
    const int* __restrict__ y, _Float16* __restrict__ w1t,
    _Float16* __restrict__ w2t, int* __restrict__ ypad,
    float* __restrict__ zero_base) {
  int idx = blockIdx.x * 256 + threadIdx.x;
  if (idx < 49152) {                       // W1 [96,512] -> W1t [512,96]
    int n = idx / 96, k = idx - n * 96;
    w1t[idx] = (_Float16)W1[k * 512 + n];
  } else if (idx < 311296) {               // W2 [512,512] -> W2t [512,512]
    int j = idx - 49152;
    int n = j / 512, k = j - n * 512;
    w2t[j] = (_Float16)W2[k * 512 + n];
  } else if (idx < 413696) {               // padded candidate_y
    int j = idx - 311296;
    int ch = j / 5120, pos = j - ch * 5120;
    ypad[j] = (pos < 5000) ? y[ch * 5000 + pos] : 0;
  } else if (idx < 547840) {
    zero_base[idx - 413696] = 0.0f;        // csq | qsq | sumexp | logits
  }
}

// ---------------- fused 2-layer encoder: enc = relu(x@W1+b1)@W2 + b2
// 64 rows/block (halves w2t L2 traffic vs 32; 4x acc tiles per aw fragment).
// A = weight cols (global, L2-hot), B = data rows (swizzled LDS).
template <int CHUNK_IN, int CHUNK_OUT>
__global__ __launch_bounds__(256, 2) void encode_kernel(
    const float* __restrict__ xn, const float* __restrict__ xc,
    const _Float16* __restrict__ w1t, const float* __restrict__ b1,
    const _Float16* __restrict__ w2t, const float* __restrict__ b2,
    _Float16* __restrict__ out, float* __restrict__ outsq) {
  __shared__ __align__(16) char lds_x[16384];  // 64 rows x 16 units(16B) swz
  __shared__ __align__(16) char lds_h[65536];  // 64 rows x 64 units(16B) swz

  const int t = threadIdx.x;
  const int R0 = blockIdx.x * 64;
  const int w = t >> 6, l = t & 63;
  const int l15 = l & 15, quad = l >> 4;
  const int ncol0 = w * 128;

  // ---- stage x (f32 -> f16, swizzled): unit kq of row holds cols kq*8..+8
#pragma unroll
  for (int it = 0; it < 4; it++) {
    int idx = it * 256 + t;
    int row = idx >> 4, kq = idx & 15;
    int pr = R0 + row;
    int ch = pr / CHUNK_OUT, pos = pr - ch * CHUNK_OUT;
    float v[8] = {0, 0, 0, 0, 0, 0, 0, 0};
    if (pos < CHUNK_IN && kq < 12) {
      int orig = ch * CHUNK_IN + pos;
      float4 f0, f1;
      if (kq < 8) {
        f0 = *(const float4*)&xn[orig * 64 + kq * 8];
        f1 = *(const float4*)&xn[orig * 64 + kq * 8 + 4];
      } else {
        f0 = *(const float4*)&xc[orig * 32 + (kq - 8) * 8];
        f1 = *(const float4*)&xc[orig * 32 + (kq - 8) * 8 + 4];
      }
      v[0] = f0.x; v[1] = f0.y; v[2] = f0.z; v[3] = f0.w;
      v[4] = f1.x; v[5] = f1.y; v[6] = f1.z; v[7] = f1.w;
    }
    f16x8 hv;
#pragma unroll
    for (int j = 0; j < 8; j++) hv[j] = (_Float16)v[j];
    *(f16x8*)&lds_x[row * 256 + (((kq ^ (row & 7)) & 15) << 4)] = hv;
  }
  __syncthreads();

  // ---- phase 1: h = x @ W1  (K=96), 4 row-tiles per wave
  f32x4 acc1[8][4];
#pragma unroll
  for (int ni = 0; ni < 8; ni++)
#pragma unroll
    for (int rt = 0; rt < 4; rt++) acc1[ni][rt] = (f32x4)(0.0f);

#pragma unroll
  for (int kt = 0; kt < 3; kt++) {
    f16x8 bx[4];
#pragma unroll
    for (int rt = 0; rt < 4; rt++) {
      int row = rt * 16 + l15;
      int kq = kt * 4 + quad;
      bx[rt] = *(const f16x8*)&lds_x[row * 256 + (((kq ^ (row & 7)) & 15) << 4)];
    }
#pragma unroll
    for (int ni = 0; ni < 8; ni++) {
      f16x8 aw = *(const f16x8*)&w1t[(ncol0 + ni * 16 + l15) * 96 + kt * 32 + quad * 8];
#pragma unroll
      for (int rt = 0; rt < 4; rt++) acc1[ni][rt] = MFMA16(aw, bx[rt], acc1[ni][rt]);
    }
  }

  // ---- epilogue 1: +b1, relu, b64 write to swizzled lds_h
#pragma unroll
  for (int ni = 0; ni < 8; ni++) {
    float4 b1v = *(const float4*)&b1[ncol0 + ni * 16 + quad * 4];
    int kq2 = (ncol0 >> 3) + ni * 2 + (quad >> 1);
#pragma unroll
    for (int rt = 0; rt < 4; rt++) {
      int row = rt * 16 + l15;
      f16x4 hv;
      hv[0] = (_Float16)fmaxf(acc1[ni][rt][0] + b1v.x, 0.0f);
      hv[1] = (_Float16)fmaxf(acc1[ni][rt][1] + b1v.y, 0.0f);
      hv[2] = (_Float16)fmaxf(acc1[ni][rt][2] + b1v.z, 0.0f);
      hv[3] = (_Float16)fmaxf(acc1[ni][rt][3] + b1v.w, 0.0f);
      int swz = (kq2 & ~7) | ((kq2 & 7) ^ (row & 7));
      *(f16x4*)&lds_h[row * 1024 + (swz << 4) + ((quad & 1) << 3)] = hv;
    }
  }
  __syncthreads();

  // ---- phase 2: enc = h @ W2  (K=512); 8 aw loads feed 32 MFMA per kt
  f32x4 acc2[8][4];
#pragma unroll
  for (int ni = 0; ni < 8; ni++)
#pragma unroll
    for (int rt = 0; rt < 4; rt++) acc2[ni][rt] = (f32x4)(0.0f);

#pragma unroll 2
  for (int kt = 0; kt < 16; kt++) {
    f16x8 bh[4];
#pragma unroll
    for (int rt = 0; rt < 4; rt++) {
      int row = rt * 16 + l15;
      int kq = kt * 4 + quad;
      int swz = (kq & ~7) | ((kq & 7) ^ (row & 7));
      bh[rt] = *(const f16x8*)&lds_h[row * 1024 + (swz << 4)];
    }
#pragma unroll
    for (int ni = 0; ni < 8; ni++) {
      f16x8 aw = *(const f16x8*)&w2t[(ncol0 + ni * 16 + l15) * 512 + kt * 32 + quad * 8];
#pragma unroll
      for (int rt = 0; rt < 4; rt++)
        acc2[ni][rt] = MFMA16(aw, bh[rt], acc2[ni][rt]);
    }
  }

  // ---- epilogue 2: +b2, b64 global store, row sum-of-squares
#pragma unroll
  for (int rt = 0; rt < 4; rt++) {
    int pr = R0 + rt * 16 + l15;
    int ch = pr / CHUNK_OUT, pos = pr - ch * CHUNK_OUT;
    bool valid = pos < CHUNK_IN;
    float s = 0.0f;
#pragma unroll
    for (int ni = 0; ni < 8; ni++) {
      float4 b2v = *(const float4*)&b2[ncol0 + ni * 16 + quad * 4];
      f16x4 ov;
      if (valid) {
        ov[0] = (_Float16)(acc2[ni][rt][0] + b2v.x);
        ov[1] = (_Float16)(acc2[ni][rt][1] + b2v.y);
        ov[2] = (_Float16)(acc2[ni][rt][2] + b2v.z);
        ov[3] = (_Float16)(acc2[ni][rt][3] + b2v.w);
#pragma unroll
        for (int r = 0; r < 4; r++) {
          float cv = (float)ov[r];
          s += cv * cv;
        }
      } else {
        ov[0] = (_Float16)0.0f; ov[1] = (_Float16)0.0f;
        ov[2] = (_Float16)0.0f; ov[3] = (_Float16)0.0f;
        s += 4.0f * 19.53125f;               // 1e4 / 512 per pad element
      }
      *(f16x4*)&out[pr * 512 + ncol0 + ni * 16 + quad * 4] = ov;
    }
    s += __shfl_xor(s, 16);
    s += __shfl_xor(s, 32);
    if (quad == 0) atomicAdd(&outsq[pr], s);  // 4 adds/row (one per wave)
  }
}

// ---------------- fused distance + reductions (barrier-free K loop)
// 2560 blocks: id -> xcd=id&7 owns cols [xcd*12800, +12800); by=(id>>3)&15
// (64 q-rows); m=id>>7 -> col-group g = xcd*20+m (640 cols = 20 tiles of 32,
// inside one 5120-chunk). q staged once in swizzled LDS; c-frags streamed
// global->VGPR (L1-line reuse across ks); acc/sume/qs persistent in regs.
__global__ __launch_bounds__(256, 2) void dist_kernel(
    const _Float16* __restrict__ q, const _Float16* __restrict__ c,
    const float* __restrict__ qsq, const float* __restrict__ csq,
    const int* __restrict__ ypad, float* __restrict__ sumexp,
    float* __restrict__ logits) {
  __shared__ __align__(16) char lds_q[65536];  // 64 rows x 64 units(16B) swz
  __shared__ float lds_logit[640];             // 64 rows x 10 classes

  const int t = threadIdx.x, w = t >> 6, l = t & 63;
  const int l31 = l & 31, half = l >> 5;
  const int id = blockIdx.x;
  const int xcd = id & 7, by = (id >> 3) & 15, m = id >> 7;
  const int g = xcd * 20 + m;
  const int row0 = by * 64, colg0 = g * 640, chunk = g >> 3;

  for (int i = t; i < 640; i += 256) lds_logit[i] = 0.0f;

  // stage q rows [row0, row0+64) into swizzled LDS (one-time, 64 KB)
#pragma unroll
  for (int it = 0; it < 16; it++) {
    int uf = it * 256 + t;
    int row = uf >> 6, u = uf & 63;
    f16x8 v = *(const f16x8*)&q[(size_t)(row0 + row) * 512 + u * 8];
    int swz = (u & ~7) | ((u & 7) ^ (row & 7));
    *(f16x8*)&lds_q[row * 1024 + (swz << 4)] = v;
  }
  __syncthreads();

  // persistent per-lane state: qs (row sq-norms), sume (chunk sumexp partials)
  float qs0[16], qs1[16], sume0[16], sume1[16];
#pragma unroll
  for (int reg = 0; reg < 16; reg++) {
    int rr = (reg & 3) + 8 * (reg >> 2) + 4 * half;
    qs0[reg] = qsq[row0 + rr];
    qs1[reg] = qsq[row0 + 32 + rr];
    sume0[reg] = 0.0f;
    sume1[reg] = 0.0f;
  }

  for (int tile = w; tile < 20; tile += 4) {
    int col0 = colg0 + tile * 32;
    const _Float16* cb = c + (size_t)(col0 + l31) * 512 + half * 8;

    f32x16 acc0 = (f32x16)(0.0f), acc1 = (f32x16)(0.0f);
    f16x8 bcur = *(const f16x8*)cb;
#pragma unroll 4
    for (int ks = 0; ks < 32; ks++) {
      f16x8 bnext = *(const f16x8*)(cb + ((ks + 1) & 31) * 16);
      int u = ks * 2 + half;
      int swz = (u & ~7) | ((u & 7) ^ (l31 & 7));
      f16x8 a0 = *(const f16x8*)&lds_q[l31 * 1024 + (swz << 4)];
      f16x8 a1 = *(const f16x8*)&lds_q[(32 + l31) * 1024 + (swz << 4)];
      acc0 = MFMA32(a0, bcur, acc0);
      acc1 = MFMA32(a1, bcur, acc1);
      bcur = bnext;
    }

    // per-tile epilogue: lane owns col = col0+l31, rows via 32x32 C-layout
    float cs = csq[col0 + l31];
    int yv = ypad[col0 + l31];
#pragma unroll
    for (int reg = 0; reg < 16; reg++) {
      int rr = (reg & 3) + 8 * (reg >> 2) + 4 * half;
      float sq0 = qs0[reg] + cs - 2.0f * acc0[reg];
      float ed0 = __expf(-sqrtf(fmaxf(sq0, 0.0f)));   // pad: d>=100 -> 0
      atomicAdd(&lds_logit[rr * 10 + yv], ed0);
      sume0[reg] += __expf(ed0);                      // pad adds exactly 1.0
      float sq1 = qs1[reg] + cs - 2.0f * acc1[reg];
      float ed1 = __expf(-sqrtf(fmaxf(sq1, 0.0f)));
      atomicAdd(&lds_logit[(32 + rr) * 10 + yv], ed1);
      sume1[reg] += __expf(ed1);
    }
  }

  // flush sumexp: reduce each (rt,reg) over the 32 cols (l31) then 1 atomic
#pragma unroll
  for (int reg = 0; reg < 16; reg++) {
    float v0 = sume0[reg], v1 = sume1[reg];
    v0 += __shfl_xor(v0, 1);  v1 += __shfl_xor(v1, 1);
    v0 += __shfl_xor(v0, 2);  v1 += __shfl_xor(v1, 2);
    v0 += __shfl_xor(v0, 4);  v1 += __shfl_xor(v1, 4);
    v0 += __shfl_xor(v0, 8);  v1 += __shfl_xor(v1, 8);
    v0 += __shfl_xor(v0, 16); v1 += __shfl_xor(v1, 16);
    if (l31 == 0) {
      int rr = (reg & 3) + 8 * (reg >> 2) + 4 * half;
      atomicAdd(&sumexp[(row0 + rr) * 20 + chunk], v0);
      atomicAdd(&sumexp[(row0 + 32 + rr) * 20 + chunk], v1);
    }
  }
  __syncthreads();
  for (int i = t; i < 640; i += 256)
    atomicAdd(&logits[row0 * 10 + i], lds_logit[i]);
}

// ---------------- finalize: out[i,k] = log(logits[i,k]) - sum_ch log(sumexp-120)
__global__ __launch_bounds__(256) void finalize_kernel(
    const float* __restrict__ logits, const float* __restrict__ sumexp,
    float* __restrict__ out) {
  int i = blockIdx.x * 256 + threadIdx.x;
  if (i >= 1024) return;
  float lse = 0.0f;
#pragma unroll
  for (int ch = 0; ch < 20; ch++) lse += logf(sumexp[i * 20 + ch] - 120.0f);
#pragma unroll
  for (int k = 0; k < 10; k++) out[i * 10 + k] = logf(logits[i * 10 + k]) - lse;
}

extern "C" void kernel_launch(void* const* d_in, const int* in_sizes, int n_in,
                              void* d_out, int out_size, void* d_ws, size_t ws_size,
                              hipStream_t stream) {
  const float* x_num = (const float*)d_in[0];
  const float* x_cat = (const float*)d_in[1];
  const float* cxn   = (const float*)d_in[2];
  const float* cxc   = (const float*)d_in[3];
  const int*   cy    = (const int*)d_in[4];
  const float* W1    = (const float*)d_in[5];
  const float* b1    = (const float*)d_in[6];
  const float* W2    = (const float*)d_in[7];
  const float* b2    = (const float*)d_in[8];
  float* out = (float*)d_out;

  char* ws = (char*)d_ws;
  _Float16* c    = (_Float16*)(ws + 0);           // 102400*512*2 = 104857600
  _Float16* qe   = (_Float16*)(ws + 104857600);   // 1024*512*2   = 1048576
  _Float16* w1t  = (_Float16*)(ws + 105906176);   // 512*96*2     = 98304
  _Float16* w2t  = (_Float16*)(ws + 106004480);   // 512*512*2    = 524288
  float*    csq  = (float*)(ws + 106528768);      // 102400*4     = 409600
  float*    qsq  = (float*)(ws + 106938368);      // 1024*4       = 4096
  float*    sume = (float*)(ws + 106942464);      // 1024*20*4    = 81920
  float*    lgts = (float*)(ws + 107024384);      // 1024*10*4    = 40960
  int*      ypad = (int*)(ws + 107065344);        // 102400*4     = 409600

  prep_kernel<<<2140, 256, 0, stream>>>(W1, W2, cy, w1t, w2t, ypad, csq);
  // candidates: 102400 padded rows / 64 = 1600 blocks
  encode_kernel<5000, 5120><<<1600, 256, 0, stream>>>(cxn, cxc, w1t, b1, w2t, b2, c, csq);
  // queries: 1024 rows / 64 = 16 blocks
  encode_kernel<(1 << 20), (1 << 20)><<<16, 256, 0, stream>>>(x_num, x_cat, w1t, b1, w2t, b2, qe, qsq);
  dist_kernel<<<2560, 256, 0, stream>>>(qe, c, qsq, csq, ypad, sume, lgts);
  finalize_kernel<<<4, 256, 0, stream>>>(lgts, sume, out);
}

// Round 5
// 576.481 us; speedup vs baseline: 1.9274x; 1.7392x over previous
//
#include <hip/hip_runtime.h>
#include <hip/hip_bf16.h>

// ModernNCA fused pipeline for MI355X (gfx950). Round 5: kill the LDS-atomic
// epilogue floor.
//
// R4 lesson: three different K-loop structures all plateau at ~760us -> the
// bottleneck was never the K-loop; it is the 105M same-address ds_add_f32
// (per-element one-hot logit scatter) serializing the LDS pipe.
// R5: logits = ed @ onehot(y) computed as a real MFMA: per 64x32 ed tile the
// wave writes ed to private LDS scratch (plain b16 writes, same-wave DS
// ordering, no barrier), builds the one-hot B-frag in registers from ypad,
// and accumulates D[row][class] in 16 VGPRs with mfma_f32_16x16x32_f16.
// Flush: 16 lds atomics/wave -> 640-word global flush into 8 per-XCD partial
// logit arrays (finalize sums them).
//
// Padding: 5000->5120 per chunk; pad rows c=0, csq=1e4 -> d>=100 -> ed==0;
// each pad adds exp(0)=1 to chunk sumexp; finalize subtracts 120.

typedef _Float16 f16x8 __attribute__((ext_vector_type(8)));
typedef _Float16 f16x4 __attribute__((ext_vector_type(4)));
typedef float f32x4 __attribute__((ext_vector_type(4)));
typedef float f32x16 __attribute__((ext_vector_type(16)));

#define MFMA16(a, b, c) __builtin_amdgcn_mfma_f32_16x16x32_f16(a, b, c, 0, 0, 0)
#define MFMA32(a, b, c) __builtin_amdgcn_mfma_f32_32x32x16_f16(a, b, c, 0, 0, 0)

// ---------------- prep: W1t/W2t transpose+cast, padded y, zero accumulators
__global__ __launch_bounds__(256) void prep_kernel(
    const float* __restrict__ W1, const float* __restrict__ W2,
    const int* __restrict__ y, _Float16* __restrict__ w1t,
    _Float16* __restrict__ w2t, int* __restrict__ ypad,
    float* __restrict__ zero_base) {
  int idx = blockIdx.x * 256 + threadIdx.x;
  if (idx < 49152) {                       // W1 [96,512] -> W1t [512,96]
    int n = idx / 96, k = idx - n * 96;
    w1t[idx] = (_Float16)W1[k * 512 + n];
  } else if (idx < 311296) {               // W2 [512,512] -> W2t [512,512]
    int j = idx - 49152;
    int n = j / 512, k = j - n * 512;
    w2t[j] = (_Float16)W2[k * 512 + n];
  } else if (idx < 413696) {               // padded candidate_y
    int j = idx - 311296;
    int ch = j / 5120, pos = j - ch * 5120;
    ypad[j] = (pos < 5000) ? y[ch * 5000 + pos] : 0;
  } else if (idx < 619520) {
    // zero: csq(102400) qsq(1024) sumexp(20480) lgts_part(81920) = 205824 f32
    zero_base[idx - 413696] = 0.0f;
  }
}

// ---------------- fused 2-layer encoder: enc = relu(x@W1+b1)@W2 + b2
// (unchanged from R4 — passes; will revisit after dist.)
template <int CHUNK_IN, int CHUNK_OUT>
__global__ __launch_bounds__(256, 2) void encode_kernel(
    const float* __restrict__ xn, const float* __restrict__ xc,
    const _Float16* __restrict__ w1t, const float* __restrict__ b1,
    const _Float16* __restrict__ w2t, const float* __restrict__ b2,
    _Float16* __restrict__ out, float* __restrict__ outsq) {
  __shared__ __align__(16) char lds_x[16384];  // 64 rows x 16 units(16B) swz
  __shared__ __align__(16) char lds_h[65536];  // 64 rows x 64 units(16B) swz

  const int t = threadIdx.x;
  const int R0 = blockIdx.x * 64;
  const int w = t >> 6, l = t & 63;
  const int l15 = l & 15, quad = l >> 4;
  const int ncol0 = w * 128;

#pragma unroll
  for (int it = 0; it < 4; it++) {
    int idx = it * 256 + t;
    int row = idx >> 4, kq = idx & 15;
    int pr = R0 + row;
    int ch = pr / CHUNK_OUT, pos = pr - ch * CHUNK_OUT;
    float v[8] = {0, 0, 0, 0, 0, 0, 0, 0};
    if (pos < CHUNK_IN && kq < 12) {
      int orig = ch * CHUNK_IN + pos;
      float4 f0, f1;
      if (kq < 8) {
        f0 = *(const float4*)&xn[orig * 64 + kq * 8];
        f1 = *(const float4*)&xn[orig * 64 + kq * 8 + 4];
      } else {
        f0 = *(const float4*)&xc[orig * 32 + (kq - 8) * 8];
        f1 = *(const float4*)&xc[orig * 32 + (kq - 8) * 8 + 4];
      }
      v[0] = f0.x; v[1] = f0.y; v[2] = f0.z; v[3] = f0.w;
      v[4] = f1.x; v[5] = f1.y; v[6] = f1.z; v[7] = f1.w;
    }
    f16x8 hv;
#pragma unroll
    for (int j = 0; j < 8; j++) hv[j] = (_Float16)v[j];
    *(f16x8*)&lds_x[row * 256 + (((kq ^ (row & 7)) & 15) << 4)] = hv;
  }
  __syncthreads();

  f32x4 acc1[8][4];
#pragma unroll
  for (int ni = 0; ni < 8; ni++)
#pragma unroll
    for (int rt = 0; rt < 4; rt++) acc1[ni][rt] = (f32x4)(0.0f);

#pragma unroll
  for (int kt = 0; kt < 3; kt++) {
    f16x8 bx[4];
#pragma unroll
    for (int rt = 0; rt < 4; rt++) {
      int row = rt * 16 + l15;
      int kq = kt * 4 + quad;
      bx[rt] = *(const f16x8*)&lds_x[row * 256 + (((kq ^ (row & 7)) & 15) << 4)];
    }
#pragma unroll
    for (int ni = 0; ni < 8; ni++) {
      f16x8 aw = *(const f16x8*)&w1t[(ncol0 + ni * 16 + l15) * 96 + kt * 32 + quad * 8];
#pragma unroll
      for (int rt = 0; rt < 4; rt++) acc1[ni][rt] = MFMA16(aw, bx[rt], acc1[ni][rt]);
    }
  }

#pragma unroll
  for (int ni = 0; ni < 8; ni++) {
    float4 b1v = *(const float4*)&b1[ncol0 + ni * 16 + quad * 4];
    int kq2 = (ncol0 >> 3) + ni * 2 + (quad >> 1);
#pragma unroll
    for (int rt = 0; rt < 4; rt++) {
      int row = rt * 16 + l15;
      f16x4 hv;
      hv[0] = (_Float16)fmaxf(acc1[ni][rt][0] + b1v.x, 0.0f);
      hv[1] = (_Float16)fmaxf(acc1[ni][rt][1] + b1v.y, 0.0f);
      hv[2] = (_Float16)fmaxf(acc1[ni][rt][2] + b1v.z, 0.0f);
      hv[3] = (_Float16)fmaxf(acc1[ni][rt][3] + b1v.w, 0.0f);
      int swz = (kq2 & ~7) | ((kq2 & 7) ^ (row & 7));
      *(f16x4*)&lds_h[row * 1024 + (swz << 4) + ((quad & 1) << 3)] = hv;
    }
  }
  __syncthreads();

  f32x4 acc2[8][4];
#pragma unroll
  for (int ni = 0; ni < 8; ni++)
#pragma unroll
    for (int rt = 0; rt < 4; rt++) acc2[ni][rt] = (f32x4)(0.0f);

#pragma unroll 2
  for (int kt = 0; kt < 16; kt++) {
    f16x8 bh[4];
#pragma unroll
    for (int rt = 0; rt < 4; rt++) {
      int row = rt * 16 + l15;
      int kq = kt * 4 + quad;
      int swz = (kq & ~7) | ((kq & 7) ^ (row & 7));
      bh[rt] = *(const f16x8*)&lds_h[row * 1024 + (swz << 4)];
    }
#pragma unroll
    for (int ni = 0; ni < 8; ni++) {
      f16x8 aw = *(const f16x8*)&w2t[(ncol0 + ni * 16 + l15) * 512 + kt * 32 + quad * 8];
#pragma unroll
      for (int rt = 0; rt < 4; rt++)
        acc2[ni][rt] = MFMA16(aw, bh[rt], acc2[ni][rt]);
    }
  }

#pragma unroll
  for (int rt = 0; rt < 4; rt++) {
    int pr = R0 + rt * 16 + l15;
    int ch = pr / CHUNK_OUT, pos = pr - ch * CHUNK_OUT;
    bool valid = pos < CHUNK_IN;
    float s = 0.0f;
#pragma unroll
    for (int ni = 0; ni < 8; ni++) {
      float4 b2v = *(const float4*)&b2[ncol0 + ni * 16 + quad * 4];
      f16x4 ov;
      if (valid) {
        ov[0] = (_Float16)(acc2[ni][rt][0] + b2v.x);
        ov[1] = (_Float16)(acc2[ni][rt][1] + b2v.y);
        ov[2] = (_Float16)(acc2[ni][rt][2] + b2v.z);
        ov[3] = (_Float16)(acc2[ni][rt][3] + b2v.w);
#pragma unroll
        for (int r = 0; r < 4; r++) {
          float cv = (float)ov[r];
          s += cv * cv;
        }
      } else {
        ov[0] = (_Float16)0.0f; ov[1] = (_Float16)0.0f;
        ov[2] = (_Float16)0.0f; ov[3] = (_Float16)0.0f;
        s += 4.0f * 19.53125f;               // 1e4 / 512 per pad element
      }
      *(f16x4*)&out[pr * 512 + ncol0 + ni * 16 + quad * 4] = ov;
    }
    s += __shfl_xor(s, 16);
    s += __shfl_xor(s, 32);
    if (quad == 0) atomicAdd(&outsq[pr], s);
  }
}

// ---------------- fused distance + reductions (MFMA logits, no per-elem atomics)
// 1280 blocks x 512 threads (8 waves). id: xcd=id&7 (owns cols [xcd*12800,
// +12800)), by=(id>>3)&15 (64 q-rows), m=id>>7 -> col-group g=xcd*10+m
// (1280 cols = 40 tiles of 32; wave w does tiles w, w+8, ...). q staged once
// in 64KB swizzled LDS; c streamed global->VGPR with a 4-deep ring; ed tile
// bounced through wave-private LDS scratch into a one-hot MFMA for logits.
__global__ __launch_bounds__(512, 2) void dist_kernel(
    const _Float16* __restrict__ q, const _Float16* __restrict__ c,
    const float* __restrict__ qsq, const float* __restrict__ csq,
    const int* __restrict__ ypad, float* __restrict__ sumexp,
    float* __restrict__ lgts_part) {
  __shared__ __align__(16) char lds_q[65536];   // 64 rows x 64 units(16B) swz
  __shared__ __align__(16) char lds_ed[32768];  // 8 waves x (64x32 f16)
  __shared__ float lds_logit[640];              // 64 rows x 10 classes
  __shared__ float lds_qsq[64];

  const int t = threadIdx.x, w = t >> 6, l = t & 63;
  const int l31 = l & 31, half = l >> 5;
  const int l15 = l & 15, quad = (l >> 4) & 3;
  const int id = blockIdx.x;
  const int xcd = id & 7, by = (id >> 3) & 15, m = id >> 7;
  const int g = xcd * 10 + m;
  const int row0 = by * 64, chunk = g >> 2;   // 4 col-groups per 5120-chunk

  for (int i = t; i < 640; i += 512) lds_logit[i] = 0.0f;
  if (t < 64) lds_qsq[t] = qsq[row0 + t];

  // stage q rows [row0, row0+64) into swizzled LDS (coalesced, one-time)
#pragma unroll
  for (int it = 0; it < 8; it++) {
    int idx = it * 512 + t;
    int row = idx >> 6, u = idx & 63;
    f16x8 v = *(const f16x8*)&q[(size_t)(row0 + row) * 512 + u * 8];
    int swz = (u & ~7) | ((u & 7) ^ (row & 7));
    *(f16x8*)&lds_q[row * 1024 + (swz << 4)] = v;
  }
  __syncthreads();

  float sume0[16], sume1[16];
  f32x4 lacc[4];
#pragma unroll
  for (int reg = 0; reg < 16; reg++) { sume0[reg] = 0.0f; sume1[reg] = 0.0f; }
#pragma unroll
  for (int mt = 0; mt < 4; mt++) lacc[mt] = (f32x4)(0.0f);

  char* edbase = lds_ed + w * 4096;   // wave-private 64x32 f16 scratch

  for (int tile = w; tile < 40; tile += 8) {
    int col0 = g * 1280 + tile * 32;
    const _Float16* cb = c + (size_t)(col0 + l31) * 512 + half * 8;

    f32x16 acc0 = (f32x16)(0.0f), acc1 = (f32x16)(0.0f);
    f16x8 br[4];
#pragma unroll
    for (int i = 0; i < 4; i++) br[i] = *(const f16x8*)(cb + i * 16);

#pragma unroll 4
    for (int ks = 0; ks < 32; ks++) {
      f16x8 bn = *(const f16x8*)(cb + ((ks + 4) & 31) * 16);
      int u = ks * 2 + half;
      int swz = (u & ~7) | ((u & 7) ^ (l31 & 7));   // (32+l31)&7 == l31&7
      f16x8 a0 = *(const f16x8*)&lds_q[l31 * 1024 + (swz << 4)];
      f16x8 a1 = *(const f16x8*)&lds_q[(32 + l31) * 1024 + (swz << 4)];
      acc0 = MFMA32(a0, br[ks & 3], acc0);
      acc1 = MFMA32(a1, br[ks & 3], acc1);
      br[ks & 3] = bn;
    }

    // epilogue: ed = exp(-dist); sumexp partials in regs; ed tile -> LDS
    float cs = csq[col0 + l31];
#pragma unroll
    for (int reg = 0; reg < 16; reg++) {
      int rr = (reg & 3) + 8 * (reg >> 2) + 4 * half;
      float qs0 = lds_qsq[rr];
      float qs1 = lds_qsq[32 + rr];
      float ed0 = __expf(-sqrtf(fmaxf(qs0 + cs - 2.0f * acc0[reg], 0.0f)));
      float ed1 = __expf(-sqrtf(fmaxf(qs1 + cs - 2.0f * acc1[reg], 0.0f)));
      sume0[reg] += __expf(ed0);     // pad cols: ed==0 -> adds exactly 1.0
      sume1[reg] += __expf(ed1);
      *(_Float16*)&edbase[rr * 64 + l31 * 2] = (_Float16)ed0;
      *(_Float16*)&edbase[(32 + rr) * 64 + l31 * 2] = (_Float16)ed1;
    }

    // one-hot B-frag from ypad (ypad in [0,10) -> lanes l15>=10 get zeros)
    int4 ya = *(const int4*)&ypad[col0 + quad * 8];
    int4 yb = *(const int4*)&ypad[col0 + quad * 8 + 4];
    f16x8 bf;
    bf[0] = (_Float16)(ya.x == l15 ? 1.0f : 0.0f);
    bf[1] = (_Float16)(ya.y == l15 ? 1.0f : 0.0f);
    bf[2] = (_Float16)(ya.z == l15 ? 1.0f : 0.0f);
    bf[3] = (_Float16)(ya.w == l15 ? 1.0f : 0.0f);
    bf[4] = (_Float16)(yb.x == l15 ? 1.0f : 0.0f);
    bf[5] = (_Float16)(yb.y == l15 ? 1.0f : 0.0f);
    bf[6] = (_Float16)(yb.z == l15 ? 1.0f : 0.0f);
    bf[7] = (_Float16)(yb.w == l15 ? 1.0f : 0.0f);

    // logits[row][class] += ed_tile @ onehot  (same-wave DS ordering: the
    // ds_reads below are ordered after this wave's ds_writes above)
#pragma unroll
    for (int mt = 0; mt < 4; mt++) {
      f16x8 af = *(const f16x8*)&edbase[(mt * 16 + l15) * 64 + quad * 16];
      lacc[mt] = MFMA16(af, bf, lacc[mt]);
    }
  }

  // flush sumexp: reduce over the 32 col-lanes, 1 atomic per row
#pragma unroll
  for (int reg = 0; reg < 16; reg++) {
    float v0 = sume0[reg], v1 = sume1[reg];
    v0 += __shfl_xor(v0, 1);  v1 += __shfl_xor(v1, 1);
    v0 += __shfl_xor(v0, 2);  v1 += __shfl_xor(v1, 2);
    v0 += __shfl_xor(v0, 4);  v1 += __shfl_xor(v1, 4);
    v0 += __shfl_xor(v0, 8);  v1 += __shfl_xor(v1, 8);
    v0 += __shfl_xor(v0, 16); v1 += __shfl_xor(v1, 16);
    if (l31 == 0) {
      int rr = (reg & 3) + 8 * (reg >> 2) + 4 * half;
      atomicAdd(&sumexp[(row0 + rr) * 20 + chunk], v0);
      atomicAdd(&sumexp[(row0 + 32 + rr) * 20 + chunk], v1);
    }
  }

  // flush logits: lacc (C-layout: col=class=l15, row=quad*4+r in mt-tile)
  if (l15 < 10) {
#pragma unroll
    for (int mt = 0; mt < 4; mt++)
#pragma unroll
      for (int r = 0; r < 4; r++)
        atomicAdd(&lds_logit[(mt * 16 + quad * 4 + r) * 10 + l15], lacc[mt][r]);
  }
  __syncthreads();
  float* lp = lgts_part + (size_t)xcd * 10240 + row0 * 10;
  for (int i = t; i < 640; i += 512) atomicAdd(&lp[i], lds_logit[i]);
}

// ---------------- finalize: out[i,k] = log(Σ_xcd lgts_part) - Σ_ch log(sumexp-120)
__global__ __launch_bounds__(256) void finalize_kernel(
    const float* __restrict__ lgts_part, const float* __restrict__ sumexp,
    float* __restrict__ out) {
  int i = blockIdx.x * 256 + threadIdx.x;
  if (i >= 1024) return;
  float lse = 0.0f;
#pragma unroll
  for (int ch = 0; ch < 20; ch++) lse += logf(sumexp[i * 20 + ch] - 120.0f);
#pragma unroll
  for (int k = 0; k < 10; k++) {
    float lg = 0.0f;
#pragma unroll
    for (int x = 0; x < 8; x++) lg += lgts_part[x * 10240 + i * 10 + k];
    out[i * 10 + k] = logf(lg) - lse;
  }
}

extern "C" void kernel_launch(void* const* d_in, const int* in_sizes, int n_in,
                              void* d_out, int out_size, void* d_ws, size_t ws_size,
                              hipStream_t stream) {
  const float* x_num = (const float*)d_in[0];
  const float* x_cat = (const float*)d_in[1];
  const float* cxn   = (const float*)d_in[2];
  const float* cxc   = (const float*)d_in[3];
  const int*   cy    = (const int*)d_in[4];
  const float* W1    = (const float*)d_in[5];
  const float* b1    = (const float*)d_in[6];
  const float* W2    = (const float*)d_in[7];
  const float* b2    = (const float*)d_in[8];
  float* out = (float*)d_out;

  char* ws = (char*)d_ws;
  _Float16* c    = (_Float16*)(ws + 0);           // 102400*512*2 = 104857600
  _Float16* qe   = (_Float16*)(ws + 104857600);   // 1024*512*2   = 1048576
  _Float16* w1t  = (_Float16*)(ws + 105906176);   // 512*96*2     = 98304
  _Float16* w2t  = (_Float16*)(ws + 106004480);   // 512*512*2    = 524288
  float*    csq  = (float*)(ws + 106528768);      // 102400*4     = 409600
  float*    qsq  = (float*)(ws + 106938368);      // 1024*4       = 4096
  float*    sume = (float*)(ws + 106942464);      // 1024*20*4    = 81920
  float*    lgtp = (float*)(ws + 107024384);      // 8*1024*10*4  = 327680
  int*      ypad = (int*)(ws + 107352064);        // 102400*4     = 409600

  prep_kernel<<<2420, 256, 0, stream>>>(W1, W2, cy, w1t, w2t, ypad, csq);
  encode_kernel<5000, 5120><<<1600, 256, 0, stream>>>(cxn, cxc, w1t, b1, w2t, b2, c, csq);
  encode_kernel<(1 << 20), (1 << 20)><<<16, 256, 0, stream>>>(x_num, x_cat, w1t, b1, w2t, b2, qe, qsq);
  dist_kernel<<<1280, 512, 0, stream>>>(qe, c, qsq, csq, ypad, sume, lgtp);
  finalize_kernel<<<4, 256, 0, stream>>>(lgtp, sume, out);
}